// Round 1
// baseline (188.467 us; speedup 1.0000x reference)
//
#include <hip/hip_runtime.h>
#include <cmath>

#define TAPE_SZ 100000
#define N_SZ    50000
#define F_SZ    32
#define B_SZ    128
#define NGRP    8          // b-groups, one per XCD (blockIdx & 7 -> XCD round-robin)
#define GSUB    16         // b's per group: 100000 rows * 32 B = 3.2 MB -> fits 4 MiB XCD L2
#define NBV     128        // n's per gather block
#define NCHUNK  ((N_SZ + NBV - 1) / NBV)   // 391 (last chunk has 80 n's)
#define NGATHER (NCHUNK * NGRP)            // 3128
#define NTAIL   512
#define TAIL_F4 1600000    // 128 b * 12500 float4 tail elements

// Manual round-to-nearest-even f32 -> bf16 bits.
static __device__ __forceinline__ unsigned short f32_to_bf16(float f) {
    unsigned int u = __float_as_uint(f);
    u = (u + 0x7fffu + ((u >> 16) & 1u)) >> 16;
    return (unsigned short)u;
}

// ---------------------------------------------------------------------------
// Kernel A: transpose tape (B x TAPE fp32) -> tapeT in XCD-partitioned layout:
// tapeT[g][row][bsub], g=b/16, bsub=b%16, bf16. Row-segment = 32 B so each
// XCD's slice (g*TAPE*16 ushorts, 3.2 MB) is contiguous and L2-resident.
// ---------------------------------------------------------------------------
__global__ __launch_bounds__(256) void transpose_tape(const float* __restrict__ in,
                                                      unsigned short* __restrict__ outT) {
    __shared__ float tile[32][129];
    const int x0 = blockIdx.x * 32;
    const int tx = threadIdx.x;       // tape-col 0..31
    const int ty = threadIdx.y;       // 0..7

    #pragma unroll
    for (int yy = ty; yy < B_SZ; yy += 8)
        tile[tx][yy] = in[(size_t)yy * TAPE_SZ + x0 + tx];
    __syncthreads();

    const int tid = ty * 32 + tx;
    const int g = tid >> 5;           // b-group 0..7
    const int l = tid & 31;           // row within tile
    unsigned short* dst = outT + ((size_t)g * TAPE_SZ + x0 + l) * GSUB;
    union { unsigned short u[8]; uint4 q; } p0, p1;
    #pragma unroll
    for (int k = 0; k < 8; ++k) {
        p0.u[k] = f32_to_bf16(tile[l][g * GSUB + k]);
        p1.u[k] = f32_to_bf16(tile[l][g * GSUB + 8 + k]);
    }
    *(uint4*)dst       = p0.q;
    *(uint4*)(dst + 8) = p1.q;
}

// ---------------------------------------------------------------------------
// Kernel B: gather-matmul, XCD-partitioned. Block (chunk, g) computes
// x[n0..n0+NBV) for b in [16g, 16g+16). Each (n,f) gather is a random 32-B
// segment inside group g's contiguous 3.2 MB slice -> L2-hit after warm-up.
// Thread = (n_local, b-half): 32 uint4 loads, 8 bf16-unpack FMA accumulators.
// Tail blocks (>= NGATHER) copy columns [N_SZ, TAPE_SZ) of tape into out.
// ---------------------------------------------------------------------------
__global__ __launch_bounds__(256) void gather_mm(const unsigned short* __restrict__ tapeT,
                                                 const float* __restrict__ weights,
                                                 const float* __restrict__ bias,
                                                 const int*   __restrict__ in_idx,
                                                 const int*   __restrict__ out_idx,
                                                 const int*   __restrict__ act_type,
                                                 const float* __restrict__ tape,
                                                 float* __restrict__ out) {
    __shared__ int   s_idx[NBV][33];   // pitch 33: conflict-free broadcast reads
    __shared__ float s_w[NBV][33];
    __shared__ float s_bias[NBV];
    __shared__ int   s_act[NBV];
    __shared__ int   s_oidx[NBV];
    __shared__ float s_x[GSUB][132];   // [b_sub][n_local], pitch 132 keeps b128 reads aligned

    const int tid = threadIdx.x;

    if (blockIdx.x >= NGATHER) {
        // ---- tail copy: columns [N_SZ, TAPE_SZ) survive into out ----
        const float4* src = (const float4*)tape;
        float4*       dst = (float4*)out;
        const int stride = NTAIL * 256;
        for (int i = (blockIdx.x - NGATHER) * 256 + tid; i < TAIL_F4; i += stride) {
            const int b = i / 12500;              // const div -> magic mul
            const int j = i - b * 12500;
            const int off = b * (TAPE_SZ / 4) + (N_SZ / 4) + j;
            dst[off] = src[off];
        }
        return;
    }

    const int g     = blockIdx.x & (NGRP - 1);
    const int chunk = blockIdx.x >> 3;
    const int n0    = chunk * NBV;
    const int nend  = min(NBV, N_SZ - n0);

    for (int t = tid; t < nend * 32; t += 256) {
        const int n = t >> 5, f = t & 31;
        s_idx[n][f] = in_idx[(size_t)n0 * 32 + t];
        s_w[n][f]   = weights[(size_t)n0 * 32 + t];
    }
    if (tid < nend) {
        s_bias[tid] = bias[n0 + tid];
        s_act[tid]  = act_type[n0 + tid];
        s_oidx[tid] = out_idx[n0 + tid];
    }
    __syncthreads();

    const int nl   = tid >> 1;            // n_local 0..127
    const int half = tid & 1;             // b-octet within group: b_sub = 8*half..8*half+7
    const unsigned short* tg = tapeT + (size_t)g * TAPE_SZ * GSUB + half * 8;

    if (nl < nend) {
        float a0 = 0.f, a1 = 0.f, a2 = 0.f, a3 = 0.f, a4 = 0.f, a5 = 0.f, a6 = 0.f, a7 = 0.f;

        #pragma unroll
        for (int fo = 0; fo < 32; fo += 8) {
            int   i8[8]; float w8[8];
            #pragma unroll
            for (int j = 0; j < 8; ++j) { i8[j] = s_idx[nl][fo + j]; w8[j] = s_w[nl][fo + j]; }
            uint4 q8[8];
            #pragma unroll
            for (int j = 0; j < 8; ++j)
                q8[j] = *(const uint4*)(tg + (size_t)i8[j] * GSUB);
            #pragma unroll
            for (int j = 0; j < 8; ++j) {
                const float w = w8[j];
                a0 = fmaf(__uint_as_float(q8[j].x << 16),         w, a0);
                a1 = fmaf(__uint_as_float(q8[j].x & 0xffff0000u), w, a1);
                a2 = fmaf(__uint_as_float(q8[j].y << 16),         w, a2);
                a3 = fmaf(__uint_as_float(q8[j].y & 0xffff0000u), w, a3);
                a4 = fmaf(__uint_as_float(q8[j].z << 16),         w, a4);
                a5 = fmaf(__uint_as_float(q8[j].z & 0xffff0000u), w, a5);
                a6 = fmaf(__uint_as_float(q8[j].w << 16),         w, a6);
                a7 = fmaf(__uint_as_float(q8[j].w & 0xffff0000u), w, a7);
            }
        }

        const float bz = s_bias[nl];
        a0 += bz; a1 += bz; a2 += bz; a3 += bz; a4 += bz; a5 += bz; a6 += bz; a7 += bz;
        if (s_act[nl] == 0) {
            a0 = fmaxf(a0, 0.f); a1 = fmaxf(a1, 0.f); a2 = fmaxf(a2, 0.f); a3 = fmaxf(a3, 0.f);
            a4 = fmaxf(a4, 0.f); a5 = fmaxf(a5, 0.f); a6 = fmaxf(a6, 0.f); a7 = fmaxf(a7, 0.f);
        } else {
            a0 = tanhf(a0); a1 = tanhf(a1); a2 = tanhf(a2); a3 = tanhf(a3);
            a4 = tanhf(a4); a5 = tanhf(a5); a6 = tanhf(a6); a7 = tanhf(a7);
        }
        const int bs = half * 8;
        s_x[bs + 0][nl] = a0; s_x[bs + 1][nl] = a1; s_x[bs + 2][nl] = a2; s_x[bs + 3][nl] = a3;
        s_x[bs + 4][nl] = a4; s_x[bs + 5][nl] = a5; s_x[bs + 6][nl] = a6; s_x[bs + 7][nl] = a7;
    }
    __syncthreads();

    // Epilogue: coalesced float4 row stores (out_idx is consecutive in this
    // problem); scalar fallback otherwise. j4 fast-varying across lanes so a
    // wave covers a 512-B contiguous span of one output row.
    const int quads = (nend + 3) >> 2;
    for (int idx = tid; idx < GSUB * quads; idx += 256) {
        int bsub, j4;
        if (nend == NBV) { bsub = idx >> 5; j4 = idx & 31; }
        else             { bsub = idx / quads; j4 = idx - bsub * quads; }
        const int nq  = j4 * 4;
        const int oc0 = s_oidx[nq];
        float* orow = out + (size_t)(g * GSUB + bsub) * TAPE_SZ;
        const bool consec = (nq + 3 < nend) &&
                            (s_oidx[nq + 1] == oc0 + 1) &&
                            (s_oidx[nq + 2] == oc0 + 2) &&
                            (s_oidx[nq + 3] == oc0 + 3) && ((oc0 & 3) == 0);
        if (consec) {
            *(float4*)(orow + oc0) = make_float4(s_x[bsub][nq + 0], s_x[bsub][nq + 1],
                                                 s_x[bsub][nq + 2], s_x[bsub][nq + 3]);
        } else {
            #pragma unroll
            for (int c = 0; c < 4; ++c)
                if (nq + c < nend) orow[s_oidx[nq + c]] = s_x[bsub][nq + c];
        }
    }
}

// ---------------------------------------------------------------------------
// Fallback (workspace too small): direct uncoalesced gather. Correct, slow.
// ---------------------------------------------------------------------------
__global__ __launch_bounds__(128) void gather_fallback(const float* __restrict__ tape,
                                                       const float* __restrict__ weights,
                                                       const float* __restrict__ bias,
                                                       const int*   __restrict__ in_idx,
                                                       const int*   __restrict__ out_idx,
                                                       const int*   __restrict__ act_type,
                                                       float* __restrict__ out) {
    const int n = blockIdx.x;
    const int b = threadIdx.x;
    float acc = 0.f;
    for (int f = 0; f < F_SZ; ++f) {
        acc += tape[(size_t)b * TAPE_SZ + in_idx[(size_t)n * F_SZ + f]] *
               weights[(size_t)n * F_SZ + f];
    }
    acc += bias[n];
    acc = (act_type[n] == 0) ? fmaxf(acc, 0.f) : tanhf(acc);
    out[(size_t)b * TAPE_SZ + out_idx[n]] = acc;
}

__global__ __launch_bounds__(256) void copy_tail_fb(const float* __restrict__ tape,
                                                    float* __restrict__ out) {
    const int n4 = (TAPE_SZ - N_SZ) / 4;
    int i = blockIdx.x * blockDim.x + threadIdx.x;
    int b = blockIdx.y;
    if (i < n4) {
        const float4* src = (const float4*)(tape + (size_t)b * TAPE_SZ + N_SZ);
        float4*       dst = (float4*)(out  + (size_t)b * TAPE_SZ + N_SZ);
        dst[i] = src[i];
    }
}

extern "C" void kernel_launch(void* const* d_in, const int* in_sizes, int n_in,
                              void* d_out, int out_size, void* d_ws, size_t ws_size,
                              hipStream_t stream) {
    const float* tape    = (const float*)d_in[0];
    const float* weights = (const float*)d_in[1];
    const float* bias    = (const float*)d_in[2];
    const int*   in_idx  = (const int*)d_in[3];
    const int*   out_idx = (const int*)d_in[4];
    const int*   act     = (const int*)d_in[5];
    float*       out     = (float*)d_out;

    const size_t need = (size_t)TAPE_SZ * B_SZ * sizeof(unsigned short);
    if (ws_size >= need) {
        unsigned short* tapeT = (unsigned short*)d_ws;
        transpose_tape<<<dim3(TAPE_SZ / 32), dim3(32, 8), 0, stream>>>(tape, tapeT);
        gather_mm<<<dim3(NGATHER + NTAIL), dim3(256), 0, stream>>>(
            tapeT, weights, bias, in_idx, out_idx, act, tape, out);
    } else {
        copy_tail_fb<<<dim3(((TAPE_SZ - N_SZ) / 4 + 255) / 256, B_SZ), 256, 0, stream>>>(tape, out);
        gather_fallback<<<dim3(N_SZ), 128, 0, stream>>>(
            tape, weights, bias, in_idx, out_idx, act, out);
    }
}

// Round 2
// 187.787 us; speedup vs baseline: 1.0036x; 1.0036x over previous
//
#include <hip/hip_runtime.h>
#include <cmath>

#define TAPE_SZ 100000
#define N_SZ    50000
#define F_SZ    32
#define B_SZ    128
#define NGRP    8          // b-groups, one per XCD (blockIdx & 7 -> XCD round-robin)
#define GSUB    16         // b's per group: 100000 rows * 32 B = 3.2 MB -> fits 4 MiB XCD L2
#define NBV     64         // n's per gather block (256 thr = 64 n x 4 b-quads)
#define NCHUNK  ((N_SZ + NBV - 1) / NBV)   // 782 (last chunk has 16 n's)
#define NGATHER (NCHUNK * NGRP)            // 6256
#define NTAIL   512
#define TAIL_F4 1600000    // 128 b * 12500 float4 tail elements

// Manual round-to-nearest-even f32 -> bf16 bits.
static __device__ __forceinline__ unsigned short f32_to_bf16(float f) {
    unsigned int u = __float_as_uint(f);
    u = (u + 0x7fffu + ((u >> 16) & 1u)) >> 16;
    return (unsigned short)u;
}

// ---------------------------------------------------------------------------
// Kernel A: transpose tape (B x TAPE fp32) -> tapeT in XCD-partitioned layout:
// tapeT[g][row][bsub], g=b/16, bsub=b%16, bf16. Row-segment = 32 B so each
// XCD's slice (TAPE*16 ushorts, 3.2 MB) is contiguous and L2-resident.
// ---------------------------------------------------------------------------
__global__ __launch_bounds__(256) void transpose_tape(const float* __restrict__ in,
                                                      unsigned short* __restrict__ outT) {
    __shared__ float tile[32][129];
    const int x0 = blockIdx.x * 32;
    const int tx = threadIdx.x;       // tape-col 0..31
    const int ty = threadIdx.y;       // 0..7

    #pragma unroll
    for (int yy = ty; yy < B_SZ; yy += 8)
        tile[tx][yy] = in[(size_t)yy * TAPE_SZ + x0 + tx];
    __syncthreads();

    const int tid = ty * 32 + tx;
    const int g = tid >> 5;           // b-group 0..7
    const int l = tid & 31;           // row within tile
    unsigned short* dst = outT + ((size_t)g * TAPE_SZ + x0 + l) * GSUB;
    union { unsigned short u[8]; uint4 q; } p0, p1;
    #pragma unroll
    for (int k = 0; k < 8; ++k) {
        p0.u[k] = f32_to_bf16(tile[l][g * GSUB + k]);
        p1.u[k] = f32_to_bf16(tile[l][g * GSUB + 8 + k]);
    }
    *(uint4*)dst       = p0.q;
    *(uint4*)(dst + 8) = p1.q;
}

// ---------------------------------------------------------------------------
// Kernel B: gather-matmul, XCD-partitioned, occupancy-first rebuild.
// Block (chunk, g): 64 n's x 16 b's. Thread = (n_local, b-quad): one uint2
// (8 B = 4 bf16 b's) per (n,f) gather; 4 accumulators.
// LDS: packed int2 (idx,weight) [64][33] = 16.9 KB; epilogue x-stage ALIASED
// over it (barrier-separated) -> ~17.7 KB total -> 8 blocks/CU (was 3 at 44 KB).
// __launch_bounds__(256,8) caps VGPR at 64 for 8 waves/SIMD.
// Tail blocks (>= NGATHER) copy columns [N_SZ, TAPE_SZ) of tape into out.
// ---------------------------------------------------------------------------
__global__ __launch_bounds__(256, 8) void gather_mm(const unsigned short* __restrict__ tapeT,
                                                    const float* __restrict__ weights,
                                                    const float* __restrict__ bias,
                                                    const int*   __restrict__ in_idx,
                                                    const int*   __restrict__ out_idx,
                                                    const int*   __restrict__ act_type,
                                                    const float* __restrict__ tape,
                                                    float* __restrict__ out) {
    __shared__ int2  s_iw[NBV][33];    // (.x = tape idx, .y = weight bits); pitch 33
    __shared__ float s_bias[NBV];
    __shared__ int   s_act[NBV];
    __shared__ int   s_oidx[NBV];
    float (*s_x)[68] = (float (*)[68])&s_iw[0][0];   // alias: 16*68*4 = 4.4 KB < 16.9 KB

    const int tid = threadIdx.x;

    if (blockIdx.x >= NGATHER) {
        // ---- tail copy: columns [N_SZ, TAPE_SZ) survive into out ----
        const float4* src = (const float4*)tape;
        float4*       dst = (float4*)out;
        const int stride = NTAIL * 256;
        for (int i = (blockIdx.x - NGATHER) * 256 + tid; i < TAIL_F4; i += stride) {
            const int b = i / 12500;              // const div -> magic mul
            const int j = i - b * 12500;
            const int off = b * (TAPE_SZ / 4) + (N_SZ / 4) + j;
            dst[off] = src[off];
        }
        return;
    }

    const int g     = blockIdx.x & (NGRP - 1);
    const int chunk = blockIdx.x >> 3;
    const int n0    = chunk * NBV;
    const int nend  = min(NBV, N_SZ - n0);

    for (int t = tid; t < nend * 32; t += 256) {
        const int n = t >> 5, f = t & 31;
        s_iw[n][f] = make_int2(in_idx[(size_t)n0 * 32 + t],
                               __float_as_int(weights[(size_t)n0 * 32 + t]));
    }
    if (tid < nend) {
        s_bias[tid] = bias[n0 + tid];
        s_act[tid]  = act_type[n0 + tid];
        s_oidx[tid] = out_idx[n0 + tid];
    }
    __syncthreads();

    const int nl = tid >> 2;              // n_local 0..63
    const int q  = tid & 3;               // b-quad: b_sub = 4q .. 4q+3
    const unsigned short* tg = tapeT + (size_t)g * TAPE_SZ * GSUB + q * 4;

    float a0 = 0.f, a1 = 0.f, a2 = 0.f, a3 = 0.f;
    if (nl < nend) {
        #pragma unroll
        for (int fo = 0; fo < 32; fo += 8) {
            int2 iw8[8];
            #pragma unroll
            for (int j = 0; j < 8; ++j) iw8[j] = s_iw[nl][fo + j];
            uint2 q8[8];
            #pragma unroll
            for (int j = 0; j < 8; ++j)
                q8[j] = *(const uint2*)(tg + (size_t)iw8[j].x * GSUB);
            #pragma unroll
            for (int j = 0; j < 8; ++j) {
                const float w = __int_as_float(iw8[j].y);
                a0 = fmaf(__uint_as_float(q8[j].x << 16),         w, a0);
                a1 = fmaf(__uint_as_float(q8[j].x & 0xffff0000u), w, a1);
                a2 = fmaf(__uint_as_float(q8[j].y << 16),         w, a2);
                a3 = fmaf(__uint_as_float(q8[j].y & 0xffff0000u), w, a3);
            }
        }
        const float bz = s_bias[nl];
        a0 += bz; a1 += bz; a2 += bz; a3 += bz;
        if (s_act[nl] == 0) {
            a0 = fmaxf(a0, 0.f); a1 = fmaxf(a1, 0.f);
            a2 = fmaxf(a2, 0.f); a3 = fmaxf(a3, 0.f);
        } else {
            a0 = tanhf(a0); a1 = tanhf(a1); a2 = tanhf(a2); a3 = tanhf(a3);
        }
    }
    __syncthreads();   // all s_iw reads complete before aliased s_x writes

    if (nl < nend) {
        const int bs = q * 4;
        s_x[bs + 0][nl] = a0; s_x[bs + 1][nl] = a1;
        s_x[bs + 2][nl] = a2; s_x[bs + 3][nl] = a3;
    }
    __syncthreads();

    // Epilogue: coalesced float4 row stores (out_idx consecutive in this
    // problem); scalar fallback otherwise. j4 fast-varying across lanes so a
    // quarter-wave covers a 256-B contiguous span of one output row.
    const int quads = (nend + 3) >> 2;
    for (int idx = tid; idx < GSUB * quads; idx += 256) {
        int bsub, j4;
        if (nend == NBV) { bsub = idx >> 4; j4 = idx & 15; }
        else             { bsub = idx / quads; j4 = idx - bsub * quads; }
        const int nq  = j4 * 4;
        const int oc0 = s_oidx[nq];
        float* orow = out + (size_t)(g * GSUB + bsub) * TAPE_SZ;
        const bool consec = (nq + 3 < nend) &&
                            (s_oidx[nq + 1] == oc0 + 1) &&
                            (s_oidx[nq + 2] == oc0 + 2) &&
                            (s_oidx[nq + 3] == oc0 + 3) && ((oc0 & 3) == 0);
        if (consec) {
            *(float4*)(orow + oc0) = make_float4(s_x[bsub][nq + 0], s_x[bsub][nq + 1],
                                                 s_x[bsub][nq + 2], s_x[bsub][nq + 3]);
        } else {
            #pragma unroll
            for (int c = 0; c < 4; ++c)
                if (nq + c < nend) orow[s_oidx[nq + c]] = s_x[bsub][nq + c];
        }
    }
}

// ---------------------------------------------------------------------------
// Fallback (workspace too small): direct uncoalesced gather. Correct, slow.
// ---------------------------------------------------------------------------
__global__ __launch_bounds__(128) void gather_fallback(const float* __restrict__ tape,
                                                       const float* __restrict__ weights,
                                                       const float* __restrict__ bias,
                                                       const int*   __restrict__ in_idx,
                                                       const int*   __restrict__ out_idx,
                                                       const int*   __restrict__ act_type,
                                                       float* __restrict__ out) {
    const int n = blockIdx.x;
    const int b = threadIdx.x;
    float acc = 0.f;
    for (int f = 0; f < F_SZ; ++f) {
        acc += tape[(size_t)b * TAPE_SZ + in_idx[(size_t)n * F_SZ + f]] *
               weights[(size_t)n * F_SZ + f];
    }
    acc += bias[n];
    acc = (act_type[n] == 0) ? fmaxf(acc, 0.f) : tanhf(acc);
    out[(size_t)b * TAPE_SZ + out_idx[n]] = acc;
}

__global__ __launch_bounds__(256) void copy_tail_fb(const float* __restrict__ tape,
                                                    float* __restrict__ out) {
    const int n4 = (TAPE_SZ - N_SZ) / 4;
    int i = blockIdx.x * blockDim.x + threadIdx.x;
    int b = blockIdx.y;
    if (i < n4) {
        const float4* src = (const float4*)(tape + (size_t)b * TAPE_SZ + N_SZ);
        float4*       dst = (float4*)(out  + (size_t)b * TAPE_SZ + N_SZ);
        dst[i] = src[i];
    }
}

extern "C" void kernel_launch(void* const* d_in, const int* in_sizes, int n_in,
                              void* d_out, int out_size, void* d_ws, size_t ws_size,
                              hipStream_t stream) {
    const float* tape    = (const float*)d_in[0];
    const float* weights = (const float*)d_in[1];
    const float* bias    = (const float*)d_in[2];
    const int*   in_idx  = (const int*)d_in[3];
    const int*   out_idx = (const int*)d_in[4];
    const int*   act     = (const int*)d_in[5];
    float*       out     = (float*)d_out;

    const size_t need = (size_t)TAPE_SZ * B_SZ * sizeof(unsigned short);
    if (ws_size >= need) {
        unsigned short* tapeT = (unsigned short*)d_ws;
        transpose_tape<<<dim3(TAPE_SZ / 32), dim3(32, 8), 0, stream>>>(tape, tapeT);
        gather_mm<<<dim3(NGATHER + NTAIL), dim3(256), 0, stream>>>(
            tapeT, weights, bias, in_idx, out_idx, act, tape, out);
    } else {
        copy_tail_fb<<<dim3(((TAPE_SZ - N_SZ) / 4 + 255) / 256, B_SZ), 256, 0, stream>>>(tape, out);
        gather_fallback<<<dim3(N_SZ), 128, 0, stream>>>(
            tape, weights, bias, in_idx, out_idx, act, out);
    }
}